// Round 1
// baseline (702.068 us; speedup 1.0000x reference)
//
#include <hip/hip_runtime.h>

namespace {

constexpr int B = 2;
constexpr int N = 200000;
constexpr int C = 16;
constexpr int D = 256;
constexpr int H = 256;
constexpr int W = 32;
constexpr int V = D * H * W;  // 2,097,152 voxels per batch

// Replicate reference op order exactly: (p - lo) / (hi - lo) * dim, trunc, clip.
__device__ __forceinline__ int voxel_of(float x, float y, float z) {
    float fx = (x - (-48.0f)) / 96.0f * 256.0f;
    float fy = (y - (-48.0f)) / 96.0f * 256.0f;
    float fz = (z - (-4.0f)) / 5.5f * 32.0f;
    int vx = (int)fx;
    int vy = (int)fy;
    int vz = (int)fz;
    vx = vx < 0 ? 0 : (vx > D - 1 ? D - 1 : vx);
    vy = vy < 0 ? 0 : (vy > H - 1 ? H - 1 : vy);
    vz = vz < 0 ? 0 : (vz > W - 1 ? W - 1 : vz);
    return (vx * H + vy) * W + vz;
}

__global__ __launch_bounds__(256) void zero_f4(float4* __restrict__ p, int n4) {
    int i = blockIdx.x * blockDim.x + threadIdx.x;
    if (i < n4) p[i] = make_float4(0.f, 0.f, 0.f, 0.f);
}

// Pass 1 over points: count, and idempotently zero the (to-be-used) sums line.
// Multiple points hitting the same voxel all write zeros -> race-safe.
__global__ __launch_bounds__(256) void count_and_clear(
    const float* __restrict__ pts, float* __restrict__ counts,
    float4* __restrict__ sums4) {
    int idx = blockIdx.x * blockDim.x + threadIdx.x;
    if (idx >= B * N) return;
    int b = idx / N;
    const float* p = pts + (size_t)idx * 3;
    int v = voxel_of(p[0], p[1], p[2]);
    size_t bv = (size_t)b * V + v;
    atomicAdd(counts + bv, 1.0f);
    float4 z = make_float4(0.f, 0.f, 0.f, 0.f);
    float4* s = sums4 + bv * 4;  // 16 floats = one 64B line per voxel
    s[0] = z; s[1] = z; s[2] = z; s[3] = z;
}

// Pass 2 over points: accumulate features into the contiguous 64B sums line.
__global__ __launch_bounds__(256) void scatter_sums(
    const float* __restrict__ pts, const float* __restrict__ fts,
    float* __restrict__ sums) {
    int idx = blockIdx.x * blockDim.x + threadIdx.x;
    if (idx >= B * N) return;
    int b = idx / N;
    const float* p = pts + (size_t)idx * 3;
    int v = voxel_of(p[0], p[1], p[2]);
    size_t base = ((size_t)b * V + v) * C;
    const float4* f4 = (const float4*)(fts + (size_t)idx * C);
    float4 f0 = f4[0], f1 = f4[1], f2 = f4[2], f3 = f4[3];
    atomicAdd(sums + base + 0,  f0.x); atomicAdd(sums + base + 1,  f0.y);
    atomicAdd(sums + base + 2,  f0.z); atomicAdd(sums + base + 3,  f0.w);
    atomicAdd(sums + base + 4,  f1.x); atomicAdd(sums + base + 5,  f1.y);
    atomicAdd(sums + base + 6,  f1.z); atomicAdd(sums + base + 7,  f1.w);
    atomicAdd(sums + base + 8,  f2.x); atomicAdd(sums + base + 9,  f2.y);
    atomicAdd(sums + base + 10, f2.z); atomicAdd(sums + base + 11, f2.w);
    atomicAdd(sums + base + 12, f3.x); atomicAdd(sums + base + 13, f3.y);
    atomicAdd(sums + base + 14, f3.z); atomicAdd(sums + base + 15, f3.w);
}

// Finalize: one thread per (b, v). Coalesced count read; sparse sums read only
// where count > 0; 16 coalesced channel-plane stores (zeros for empty voxels).
__global__ __launch_bounds__(256) void finalize(
    const float* __restrict__ counts, const float4* __restrict__ sums4,
    float* __restrict__ out) {
    int t = blockIdx.x * blockDim.x + threadIdx.x;
    if (t >= B * V) return;
    int b = t >> 21;        // V = 2^21
    int v = t & (V - 1);
    float cnt = counts[t];
    float vals[16];
#pragma unroll
    for (int c = 0; c < 16; ++c) vals[c] = 0.f;
    if (cnt > 0.f) {
        const float4* s = sums4 + (size_t)t * 4;
        float4 s0 = s[0], s1 = s[1], s2 = s[2], s3 = s[3];
        vals[0]  = s0.x / cnt; vals[1]  = s0.y / cnt;
        vals[2]  = s0.z / cnt; vals[3]  = s0.w / cnt;
        vals[4]  = s1.x / cnt; vals[5]  = s1.y / cnt;
        vals[6]  = s1.z / cnt; vals[7]  = s1.w / cnt;
        vals[8]  = s2.x / cnt; vals[9]  = s2.y / cnt;
        vals[10] = s2.z / cnt; vals[11] = s2.w / cnt;
        vals[12] = s3.x / cnt; vals[13] = s3.y / cnt;
        vals[14] = s3.z / cnt; vals[15] = s3.w / cnt;
    }
    float* o = out + (size_t)b * C * V + v;
#pragma unroll
    for (int c = 0; c < 16; ++c) o[(size_t)c * V] = vals[c];
}

// ---- Fallback path (workspace too small for [B][V][C] sums): accumulate
// f/count directly into d_out with strided atomics. Slower, still correct.
__global__ __launch_bounds__(256) void count_only(
    const float* __restrict__ pts, float* __restrict__ counts) {
    int idx = blockIdx.x * blockDim.x + threadIdx.x;
    if (idx >= B * N) return;
    int b = idx / N;
    const float* p = pts + (size_t)idx * 3;
    int v = voxel_of(p[0], p[1], p[2]);
    atomicAdd(counts + (size_t)b * V + v, 1.0f);
}

__global__ __launch_bounds__(256) void scatter_direct(
    const float* __restrict__ pts, const float* __restrict__ fts,
    const float* __restrict__ counts, float* __restrict__ out) {
    int idx = blockIdx.x * blockDim.x + threadIdx.x;
    if (idx >= B * N) return;
    int b = idx / N;
    const float* p = pts + (size_t)idx * 3;
    int v = voxel_of(p[0], p[1], p[2]);
    float cnt = counts[(size_t)b * V + v];
    const float* f = fts + (size_t)idx * C;
    float* o = out + (size_t)b * C * V + v;
#pragma unroll
    for (int c = 0; c < 16; ++c) atomicAdd(o + (size_t)c * V, f[c] / cnt);
}

}  // namespace

extern "C" void kernel_launch(void* const* d_in, const int* in_sizes, int n_in,
                              void* d_out, int out_size, void* d_ws, size_t ws_size,
                              hipStream_t stream) {
    const float* pts = (const float*)d_in[0];   // [B, N, 3]
    const float* fts = (const float*)d_in[1];   // [B, N, C]
    float* out = (float*)d_out;                 // [B, C, D, H, W]

    const int n_pts = B * N;                                  // 400,000
    const int pt_blocks = (n_pts + 255) / 256;
    const size_t counts_bytes = (size_t)B * V * sizeof(float);           // 16 MiB
    const size_t sums_bytes = (size_t)B * V * C * sizeof(float);         // 256 MiB

    float* counts = (float*)d_ws;

    if (ws_size >= counts_bytes + sums_bytes) {
        // Fast path: channel-contiguous sums in workspace.
        float* sums = counts + (size_t)B * V;

        int counts_f4 = (B * V) / 4;  // 1,048,576
        zero_f4<<<(counts_f4 + 255) / 256, 256, 0, stream>>>((float4*)counts, counts_f4);

        count_and_clear<<<pt_blocks, 256, 0, stream>>>(pts, counts, (float4*)sums);
        scatter_sums<<<pt_blocks, 256, 0, stream>>>(pts, fts, sums);

        int vox_blocks = (B * V + 255) / 256;  // 16,384
        finalize<<<vox_blocks, 256, 0, stream>>>(counts, (const float4*)sums, out);
    } else {
        // Fallback: accumulate f/count directly into out ([B][C][V] layout).
        int counts_f4 = (B * V) / 4;
        zero_f4<<<(counts_f4 + 255) / 256, 256, 0, stream>>>((float4*)counts, counts_f4);
        int out_f4 = out_size / 4;  // 16,777,216
        zero_f4<<<(out_f4 + 255) / 256, 256, 0, stream>>>((float4*)out, out_f4);

        count_only<<<pt_blocks, 256, 0, stream>>>(pts, counts);
        scatter_direct<<<pt_blocks, 256, 0, stream>>>(pts, fts, counts, out);
    }
}

// Round 2
// 332.473 us; speedup vs baseline: 2.1117x; 2.1117x over previous
//
#include <hip/hip_runtime.h>

namespace {

constexpr int B = 2;
constexpr int N = 200000;
constexpr int C = 16;
constexpr int D = 256;
constexpr int H = 256;
constexpr int W = 32;
constexpr int V = D * H * W;    // 2^21 voxels per batch
constexpr int BV = B * V;       // 4,194,304
constexpr unsigned NIL = 0xFFFFFFFFu;

// Replicate reference op order exactly: (p - lo) / (hi - lo) * dim, trunc, clip.
// (This exact formulation gave absmax 0 in round 1 — do not change.)
__device__ __forceinline__ int voxel_of(float x, float y, float z) {
    float fx = (x - (-48.0f)) / 96.0f * 256.0f;
    float fy = (y - (-48.0f)) / 96.0f * 256.0f;
    float fz = (z - (-4.0f)) / 5.5f * 32.0f;
    int vx = (int)fx;
    int vy = (int)fy;
    int vz = (int)fz;
    vx = vx < 0 ? 0 : (vx > D - 1 ? D - 1 : vx);
    vy = vy < 0 ? 0 : (vy > H - 1 ? H - 1 : vy);
    vz = vz < 0 ? 0 : (vz > W - 1 ? W - 1 : vz);
    return (vx * H + vy) * W + vz;
}

__global__ __launch_bounds__(256) void init_head(uint4* __restrict__ head4, int n4) {
    int i = blockIdx.x * blockDim.x + threadIdx.x;
    if (i < n4) head4[i] = make_uint4(NIL, NIL, NIL, NIL);
}

// One atomicExch per point: push point idx onto its voxel's intrusive list.
__global__ __launch_bounds__(256) void build_list(
    const float* __restrict__ pts, unsigned* __restrict__ head,
    unsigned* __restrict__ nxt) {
    int idx = blockIdx.x * blockDim.x + threadIdx.x;
    if (idx >= B * N) return;
    const float* p = pts + (size_t)idx * 3;
    int v = voxel_of(p[0], p[1], p[2]);
    int b = idx / N;
    unsigned old = atomicExch(head + (size_t)b * V + v, (unsigned)idx);
    nxt[idx] = old;
}

// One thread per 4 consecutive voxels: walk lists, gather features, mean, store.
__global__ __launch_bounds__(256) void finalize(
    const uint4* __restrict__ head4, const unsigned* __restrict__ nxt,
    const float4* __restrict__ fts4, float* __restrict__ out) {
    int g = blockIdx.x * blockDim.x + threadIdx.x;
    if (g >= BV / 4) return;
    uint4 h4 = head4[g];
    int t0 = g * 4;               // first (b,v) flat index of this group
    int b = t0 >> 21;             // V = 2^21
    int v = t0 & (V - 1);

    float vals[16][4];
#pragma unroll
    for (int c = 0; c < 16; ++c)
#pragma unroll
        for (int j = 0; j < 4; ++j) vals[c][j] = 0.f;

    unsigned hs[4] = {h4.x, h4.y, h4.z, h4.w};
#pragma unroll
    for (int j = 0; j < 4; ++j) {
        unsigned h = hs[j];
        if (h == NIL) continue;
        float s[16];
#pragma unroll
        for (int c = 0; c < 16; ++c) s[c] = 0.f;
        float cnt = 0.f;
        while (h != NIL) {
            const float4* f = fts4 + (size_t)h * 4;
            float4 f0 = f[0], f1 = f[1], f2 = f[2], f3 = f[3];
            s[0]  += f0.x; s[1]  += f0.y; s[2]  += f0.z; s[3]  += f0.w;
            s[4]  += f1.x; s[5]  += f1.y; s[6]  += f1.z; s[7]  += f1.w;
            s[8]  += f2.x; s[9]  += f2.y; s[10] += f2.z; s[11] += f2.w;
            s[12] += f3.x; s[13] += f3.y; s[14] += f3.z; s[15] += f3.w;
            cnt += 1.f;
            h = nxt[h];
        }
#pragma unroll
        for (int c = 0; c < 16; ++c) vals[c][j] = s[c] / cnt;
    }

    float* obase = out + (size_t)b * C * V + v;
#pragma unroll
    for (int c = 0; c < 16; ++c) {
        float4 o = make_float4(vals[c][0], vals[c][1], vals[c][2], vals[c][3]);
        *(float4*)(obase + (size_t)c * V) = o;
    }
}

// ---- Fallback (tiny-workspace safety net): direct strided atomics into out.
__global__ __launch_bounds__(256) void zero_f4(float4* __restrict__ p, int n4) {
    int i = blockIdx.x * blockDim.x + threadIdx.x;
    if (i < n4) p[i] = make_float4(0.f, 0.f, 0.f, 0.f);
}

__global__ __launch_bounds__(256) void count_only(
    const float* __restrict__ pts, float* __restrict__ counts) {
    int idx = blockIdx.x * blockDim.x + threadIdx.x;
    if (idx >= B * N) return;
    int b = idx / N;
    const float* p = pts + (size_t)idx * 3;
    int v = voxel_of(p[0], p[1], p[2]);
    atomicAdd(counts + (size_t)b * V + v, 1.0f);
}

__global__ __launch_bounds__(256) void scatter_direct(
    const float* __restrict__ pts, const float* __restrict__ fts,
    const float* __restrict__ counts, float* __restrict__ out) {
    int idx = blockIdx.x * blockDim.x + threadIdx.x;
    if (idx >= B * N) return;
    int b = idx / N;
    const float* p = pts + (size_t)idx * 3;
    int v = voxel_of(p[0], p[1], p[2]);
    float cnt = counts[(size_t)b * V + v];
    const float* f = fts + (size_t)idx * C;
    float* o = out + (size_t)b * C * V + v;
#pragma unroll
    for (int c = 0; c < 16; ++c) atomicAdd(o + (size_t)c * V, f[c] / cnt);
}

}  // namespace

extern "C" void kernel_launch(void* const* d_in, const int* in_sizes, int n_in,
                              void* d_out, int out_size, void* d_ws, size_t ws_size,
                              hipStream_t stream) {
    const float* pts = (const float*)d_in[0];   // [B, N, 3]
    const float* fts = (const float*)d_in[1];   // [B, N, C]
    float* out = (float*)d_out;                 // [B, C, D, H, W]

    const int n_pts = B * N;                    // 400,000
    const int pt_blocks = (n_pts + 255) / 256;

    const size_t head_bytes = (size_t)BV * sizeof(unsigned);      // 16.8 MB
    const size_t nxt_bytes = (size_t)n_pts * sizeof(unsigned);    // 1.6 MB

    if (ws_size >= head_bytes + nxt_bytes) {
        unsigned* head = (unsigned*)d_ws;
        unsigned* nxt = head + (size_t)BV;

        int head_n4 = BV / 4;  // 1,048,576
        init_head<<<(head_n4 + 255) / 256, 256, 0, stream>>>((uint4*)head, head_n4);
        build_list<<<pt_blocks, 256, 0, stream>>>(pts, head, nxt);

        int fin_threads = BV / 4;  // 1,048,576 (one per 4 voxels)
        finalize<<<(fin_threads + 255) / 256, 256, 0, stream>>>(
            (const uint4*)head, nxt, (const float4*)fts, out);
    } else {
        // Safety net: direct atomic accumulation into out.
        float* counts = (float*)d_ws;
        int counts_f4 = BV / 4;
        zero_f4<<<(counts_f4 + 255) / 256, 256, 0, stream>>>((float4*)counts, counts_f4);
        int out_f4 = out_size / 4;
        zero_f4<<<(out_f4 + 255) / 256, 256, 0, stream>>>((float4*)out, out_f4);
        count_only<<<pt_blocks, 256, 0, stream>>>(pts, counts);
        scatter_direct<<<pt_blocks, 256, 0, stream>>>(pts, fts, counts, out);
    }
}